// Round 1
// baseline (407.288 us; speedup 1.0000x reference)
//
#include <hip/hip_runtime.h>
#include <math.h>

#define LN_EPS 1e-3f

__device__ __forceinline__ float silu_f(float x) { return x / (1.f + expf(-x)); }

__device__ __forceinline__ float sgnp(float a, float b) {
    float sa = (float)((a > 0.f) - (a < 0.f));
    float sb = (float)((b > 0.f) - (b < 0.f));
    return sa * sb;
}

// ---------------- Kernel 1: conv1 (W=5, stride=3, SAME, 512->128) + LN + SiLU
// grid = 5 seq * 40 tiles, block = 128 threads, 16 output positions per block.
// pad_lo = 1: out[t] = sum_{kw} x[3t - 1 + kw]
__global__ __launch_bounds__(128) void k_conv1(
    const float* __restrict__ values,   // (4,1920,512)
    const float* __restrict__ symbols,  // (1920,512)
    const float* __restrict__ w1,       // (5,512,128)
    const float* __restrict__ b1,       // (128)
    const float* __restrict__ g1,       // (128)
    const float* __restrict__ bt1,      // (128)
    float* __restrict__ h1)             // (5,640,128)
{
    const int T_IN = 1920, E = 512;
    int seq  = blockIdx.x / 40;
    int tile = blockIdx.x % 40;
    int t0 = tile * 16;
    const float* x = (seq < 4) ? (values + (size_t)seq * T_IN * E) : symbols;
    int p0 = 3 * t0 - 1;

    __shared__ float xs[51][128];   // 51 input positions x 128 ci chunk

    int tid  = threadIdx.x;
    int c4   = tid & 31;   // channel group: c = 4*c4
    int trow = tid >> 5;   // 0..3 ; thread handles t = t0 + trow + 4k

    float acc[4][4];
    #pragma unroll
    for (int k = 0; k < 4; k++)
        #pragma unroll
        for (int e = 0; e < 4; e++) acc[k][e] = 0.f;

    for (int cb = 0; cb < 512; cb += 128) {
        __syncthreads();
        for (int idx = tid; idx < 51 * 32; idx += 128) {
            int p = idx >> 5, cc4 = idx & 31;
            int gp = p0 + p;
            float4 v = make_float4(0.f, 0.f, 0.f, 0.f);
            if (gp >= 0 && gp < T_IN)
                v = *(const float4*)(x + (size_t)gp * E + cb + cc4 * 4);
            *(float4*)&xs[p][cc4 * 4] = v;
        }
        __syncthreads();

        for (int ci = 0; ci < 128; ci++) {
            float xv[20];
            #pragma unroll
            for (int k = 0; k < 4; k++)
                #pragma unroll
                for (int kw = 0; kw < 5; kw++)
                    xv[k * 5 + kw] = xs[3 * trow + 12 * k + kw][ci];
            #pragma unroll
            for (int kw = 0; kw < 5; kw++) {
                float4 w = *(const float4*)(w1 + ((size_t)(kw * 512 + cb + ci)) * 128 + 4 * c4);
                #pragma unroll
                for (int k = 0; k < 4; k++) {
                    float xvv = xv[k * 5 + kw];
                    acc[k][0] += xvv * w.x;
                    acc[k][1] += xvv * w.y;
                    acc[k][2] += xvv * w.z;
                    acc[k][3] += xvv * w.w;
                }
            }
        }
    }

    float4 bias = *(const float4*)(b1 + 4 * c4);
    float4 gam  = *(const float4*)(g1 + 4 * c4);
    float4 bet  = *(const float4*)(bt1 + 4 * c4);

    #pragma unroll
    for (int k = 0; k < 4; k++) {
        acc[k][0] += bias.x; acc[k][1] += bias.y;
        acc[k][2] += bias.z; acc[k][3] += bias.w;
        float s1 = acc[k][0] + acc[k][1] + acc[k][2] + acc[k][3];
        float s2 = acc[k][0]*acc[k][0] + acc[k][1]*acc[k][1]
                 + acc[k][2]*acc[k][2] + acc[k][3]*acc[k][3];
        // reduce over the 32-lane group holding this t (half-wave)
        #pragma unroll
        for (int m = 16; m >= 1; m >>= 1) {
            s1 += __shfl_xor(s1, m, 64);
            s2 += __shfl_xor(s2, m, 64);
        }
        float mean = s1 * (1.f / 128.f);
        float var  = s2 * (1.f / 128.f) - mean * mean;
        float rs   = rsqrtf(var + LN_EPS);
        int t = t0 + trow + 4 * k;
        float4 out;
        out.x = silu_f((acc[k][0] - mean) * rs * gam.x + bet.x);
        out.y = silu_f((acc[k][1] - mean) * rs * gam.y + bet.y);
        out.z = silu_f((acc[k][2] - mean) * rs * gam.z + bet.z);
        out.w = silu_f((acc[k][3] - mean) * rs * gam.w + bet.w);
        *(float4*)(h1 + ((size_t)seq * 640 + t) * 128 + 4 * c4) = out;
    }
}

// ---------------- Kernel 2: conv2 (W=3, stride=5, SAME->no pad, 128->1024) + LN + SiLU
// grid = 5 seq * 32 tiles, block = 256, 4 output positions per block.
// out[t] = sum_{kw} x[5t + kw]
__global__ __launch_bounds__(256) void k_conv2(
    const float* __restrict__ h1,   // (5,640,128)
    const float* __restrict__ w2,   // (3,128,1024)
    const float* __restrict__ b2,   // (1024)
    const float* __restrict__ g2,
    const float* __restrict__ bt2,
    float* __restrict__ vp,         // (4,128,1024) -> d_out second half
    float* __restrict__ sp)         // (128,1024)   -> ws
{
    int seq  = blockIdx.x >> 5;
    int tile = blockIdx.x & 31;
    int t0 = tile * 4;
    const float* x = h1 + (size_t)seq * 640 * 128;

    __shared__ float xs[18][128];
    int tid = threadIdx.x;

    for (int idx = tid; idx < 18 * 32; idx += 256) {
        int p = idx >> 5, cc4 = idx & 31;
        *(float4*)&xs[p][cc4 * 4] =
            *(const float4*)(x + (size_t)(5 * t0 + p) * 128 + cc4 * 4);
    }
    __syncthreads();

    float acc[4][4];   // [j = t-offset][e], c = 4*tid + e
    #pragma unroll
    for (int j = 0; j < 4; j++)
        #pragma unroll
        for (int e = 0; e < 4; e++) acc[j][e] = 0.f;

    for (int ci = 0; ci < 128; ci++) {
        float xv[12];
        #pragma unroll
        for (int j = 0; j < 4; j++)
            #pragma unroll
            for (int kw = 0; kw < 3; kw++)
                xv[j * 3 + kw] = xs[5 * j + kw][ci];
        #pragma unroll
        for (int kw = 0; kw < 3; kw++) {
            float4 w = *(const float4*)(w2 + ((size_t)(kw * 128 + ci)) * 1024 + 4 * tid);
            #pragma unroll
            for (int j = 0; j < 4; j++) {
                float xvv = xv[j * 3 + kw];
                acc[j][0] += xvv * w.x;
                acc[j][1] += xvv * w.y;
                acc[j][2] += xvv * w.z;
                acc[j][3] += xvv * w.w;
            }
        }
    }

    float4 bias = *(const float4*)(b2 + 4 * tid);
    float4 gam  = *(const float4*)(g2 + 4 * tid);
    float4 bet  = *(const float4*)(bt2 + 4 * tid);

    __shared__ float red[4][4][2];  // [wave][j][{s1,s2}]
    int lane = tid & 63, wv = tid >> 6;

    float s1[4], s2[4];
    #pragma unroll
    for (int j = 0; j < 4; j++) {
        acc[j][0] += bias.x; acc[j][1] += bias.y;
        acc[j][2] += bias.z; acc[j][3] += bias.w;
        s1[j] = acc[j][0] + acc[j][1] + acc[j][2] + acc[j][3];
        s2[j] = acc[j][0]*acc[j][0] + acc[j][1]*acc[j][1]
              + acc[j][2]*acc[j][2] + acc[j][3]*acc[j][3];
    }
    #pragma unroll
    for (int m = 32; m >= 1; m >>= 1) {
        #pragma unroll
        for (int j = 0; j < 4; j++) {
            s1[j] += __shfl_xor(s1[j], m, 64);
            s2[j] += __shfl_xor(s2[j], m, 64);
        }
    }
    if (lane == 0) {
        #pragma unroll
        for (int j = 0; j < 4; j++) { red[wv][j][0] = s1[j]; red[wv][j][1] = s2[j]; }
    }
    __syncthreads();

    #pragma unroll
    for (int j = 0; j < 4; j++) {
        float S1 = red[0][j][0] + red[1][j][0] + red[2][j][0] + red[3][j][0];
        float S2 = red[0][j][1] + red[1][j][1] + red[2][j][1] + red[3][j][1];
        float mean = S1 * (1.f / 1024.f);
        float var  = S2 * (1.f / 1024.f) - mean * mean;
        float rs   = rsqrtf(var + LN_EPS);
        float4 out;
        out.x = silu_f((acc[j][0] - mean) * rs * gam.x + bet.x);
        out.y = silu_f((acc[j][1] - mean) * rs * gam.y + bet.y);
        out.z = silu_f((acc[j][2] - mean) * rs * gam.z + bet.z);
        out.w = silu_f((acc[j][3] - mean) * rs * gam.w + bet.w);
        int t = t0 + j;
        if (seq < 4)
            *(float4*)(vp + ((size_t)seq * 128 + t) * 1024 + 4 * tid) = out;
        else
            *(float4*)(sp + (size_t)t * 1024 + 4 * tid) = out;
    }
}

// ---------------- Kernel 3: sign-similarity attention
// S[b,j,i] = mean_d sign(vp[b,i,d]) * sign(vp[b,i,d] + sp[j,d])
// scores = softmax_i(S); ao[b,j,d] = sum_i scores * vp[b,i,d]; O = silu(ao * sp[j,d])
// grid = 4*128 blocks (one per (b,j)), block = 256.
__global__ __launch_bounds__(256) void k_attn(
    const float* __restrict__ vp,   // (4,128,1024)
    const float* __restrict__ sp,   // (128,1024)
    float* __restrict__ O)          // (4,128,1024)
{
    int b = blockIdx.x >> 7;
    int j = blockIdx.x & 127;
    int tid = threadIdx.x, lane = tid & 63, wv = tid >> 6;

    __shared__ float ps[128][4];
    __shared__ float scores[128];
    __shared__ float redm[4];
    __shared__ float reds[4];

    float4 sp4 = *(const float4*)(sp + (size_t)j * 1024 + 4 * tid);
    const float* vpb = vp + (size_t)b * 128 * 1024;

    for (int i = 0; i < 128; i++) {
        float4 v = *(const float4*)(vpb + (size_t)i * 1024 + 4 * tid);
        float p = sgnp(v.x, v.x + sp4.x) + sgnp(v.y, v.y + sp4.y)
                + sgnp(v.z, v.z + sp4.z) + sgnp(v.w, v.w + sp4.w);
        #pragma unroll
        for (int m = 32; m >= 1; m >>= 1) p += __shfl_xor(p, m, 64);
        if (lane == 0) ps[i][wv] = p;
    }
    __syncthreads();

    float myS = 0.f, s = -INFINITY;
    if (tid < 128) {
        myS = (ps[tid][0] + ps[tid][1] + ps[tid][2] + ps[tid][3]) * (1.f / 1024.f);
        s = myS;
    }
    float mx = s;
    #pragma unroll
    for (int m = 32; m >= 1; m >>= 1) mx = fmaxf(mx, __shfl_xor(mx, m, 64));
    if (lane == 0) redm[wv] = mx;
    __syncthreads();
    mx = fmaxf(fmaxf(redm[0], redm[1]), fmaxf(redm[2], redm[3]));

    float e = (tid < 128) ? expf(myS - mx) : 0.f;
    float ssum = e;
    #pragma unroll
    for (int m = 32; m >= 1; m >>= 1) ssum += __shfl_xor(ssum, m, 64);
    if (lane == 0) reds[wv] = ssum;
    __syncthreads();
    float total = reds[0] + reds[1] + reds[2] + reds[3];
    if (tid < 128) scores[tid] = e / total;
    __syncthreads();

    float4 ao = make_float4(0.f, 0.f, 0.f, 0.f);
    for (int i = 0; i < 128; i++) {
        float sc = scores[i];
        float4 v = *(const float4*)(vpb + (size_t)i * 1024 + 4 * tid);
        ao.x += sc * v.x; ao.y += sc * v.y; ao.z += sc * v.z; ao.w += sc * v.w;
    }
    float4 o;
    o.x = silu_f(ao.x * sp4.x);
    o.y = silu_f(ao.y * sp4.y);
    o.z = silu_f(ao.z * sp4.z);
    o.w = silu_f(ao.w * sp4.w);
    *(float4*)(O + ((size_t)b * 128 + j) * 1024 + 4 * tid) = o;
}

extern "C" void kernel_launch(void* const* d_in, const int* in_sizes, int n_in,
                              void* d_out, int out_size, void* d_ws, size_t ws_size,
                              hipStream_t stream) {
    const float* values  = (const float*)d_in[0];
    const float* symbols = (const float*)d_in[1];
    const float* conv1_w = (const float*)d_in[2];
    const float* conv1_b = (const float*)d_in[3];
    const float* ln1_g   = (const float*)d_in[4];
    const float* ln1_b   = (const float*)d_in[5];
    const float* conv2_w = (const float*)d_in[6];
    const float* conv2_b = (const float*)d_in[7];
    const float* ln2_g   = (const float*)d_in[8];
    const float* ln2_b   = (const float*)d_in[9];

    float* out = (float*)d_out;
    float* O   = out;                       // (4,128,1024)
    float* vp  = out + 4 * 128 * 1024;      // (4,128,1024) = values_projected

    float* h1 = (float*)d_ws;               // (5,640,128) = 409600 floats
    float* sp = h1 + 5 * 640 * 128;         // (128,1024)  = 131072 floats

    k_conv1<<<200, 128, 0, stream>>>(values, symbols, conv1_w, conv1_b, ln1_g, ln1_b, h1);
    k_conv2<<<160, 256, 0, stream>>>(h1, conv2_w, conv2_b, ln2_g, ln2_b, vp, sp);
    k_attn<<<512, 256, 0, stream>>>(vp, sp, O);
}

// Round 2
// 236.567 us; speedup vs baseline: 1.7217x; 1.7217x over previous
//
#include <hip/hip_runtime.h>
#include <math.h>

#define LN_EPS 1e-3f

__device__ __forceinline__ float silu_f(float x) { return x / (1.f + expf(-x)); }

__device__ __forceinline__ int mism1(float a, float s) {
    unsigned ua = __float_as_uint(a);
    unsigned ub = __float_as_uint(a + s);
    return (int)((ua ^ ub) >> 31);
}

// ---------------- Kernel 1a: conv1 split-K partial GEMM
// out[t,co] partial over ci-chunk kc: sum_{kw,ci in chunk} x[3t-1+kw, ci] * w1[kw,ci,co]
// grid = 5 seq * 20 ptiles(32 pos) * 8 kchunks(64 ci) = 800 blocks, 256 threads.
__global__ __launch_bounds__(256) void k_conv1p(
    const float* __restrict__ values,   // (4,1920,512)
    const float* __restrict__ symbols,  // (1920,512)
    const float* __restrict__ w1,       // (5,512,128)
    float* __restrict__ part)           // (8,3200,128)
{
    const int T_IN = 1920, E = 512;
    int kc    = blockIdx.x & 7;
    int ptile = (blockIdx.x >> 3) % 20;
    int seq   = blockIdx.x / (8 * 20);
    int t0  = ptile * 32;
    int ci0 = kc * 64;
    const float* x = (seq < 4) ? (values + (size_t)seq * T_IN * E) : symbols;
    int p0 = 3 * t0 - 1;

    __shared__ float xs[98][64];   // input positions x ci-chunk

    int tid  = threadIdx.x;
    int c4   = tid & 31;   // co = 4*c4
    int trow = tid >> 5;   // 0..7 ; positions t0 + 4*trow + dt, dt=0..3

    // stage x tile
    for (int idx = tid; idx < 98 * 16; idx += 256) {
        int p = idx >> 4, g = idx & 15;
        int gp = p0 + p;
        float4 v = make_float4(0.f, 0.f, 0.f, 0.f);
        if (gp >= 0 && gp < T_IN)
            v = *(const float4*)(x + (size_t)gp * E + ci0 + 4 * g);
        *(float4*)&xs[p][4 * g] = v;
    }
    __syncthreads();

    float acc[4][4];
    #pragma unroll
    for (int k = 0; k < 4; k++)
        #pragma unroll
        for (int e = 0; e < 4; e++) acc[k][e] = 0.f;

    for (int ci = 0; ci < 64; ci++) {
        float xv[14];
        #pragma unroll
        for (int m = 0; m < 14; m++) xv[m] = xs[12 * trow + m][ci];
        #pragma unroll
        for (int kw = 0; kw < 5; kw++) {
            float4 w = *(const float4*)(w1 + ((size_t)(kw * 512 + ci0 + ci)) * 128 + 4 * c4);
            #pragma unroll
            for (int dt = 0; dt < 4; dt++) {
                float xvv = xv[3 * dt + kw];
                acc[dt][0] += xvv * w.x;
                acc[dt][1] += xvv * w.y;
                acc[dt][2] += xvv * w.z;
                acc[dt][3] += xvv * w.w;
            }
        }
    }

    #pragma unroll
    for (int dt = 0; dt < 4; dt++) {
        int t = t0 + 4 * trow + dt;
        *(float4*)(part + (((size_t)kc * 3200 + seq * 640 + t)) * 128 + 4 * c4) =
            make_float4(acc[dt][0], acc[dt][1], acc[dt][2], acc[dt][3]);
    }
}

// ---------------- Kernel 1b: reduce 8 partials + bias + LN(128) + SiLU -> h1
// grid = 400 blocks, 256 threads, 8 positions/block.
__global__ __launch_bounds__(256) void k_conv1r(
    const float* __restrict__ part,  // (8,3200,128)
    const float* __restrict__ b1,
    const float* __restrict__ g1,
    const float* __restrict__ bt1,
    float* __restrict__ h1)          // (5,640,128) == (3200,128)
{
    int tid = threadIdx.x;
    int c4  = tid & 31;
    int pr  = tid >> 5;
    int pos = blockIdx.x * 8 + pr;   // 0..3199

    float4 a = make_float4(0.f, 0.f, 0.f, 0.f);
    #pragma unroll
    for (int kc = 0; kc < 8; kc++) {
        float4 p = *(const float4*)(part + (((size_t)kc * 3200 + pos)) * 128 + 4 * c4);
        a.x += p.x; a.y += p.y; a.z += p.z; a.w += p.w;
    }
    float4 bias = *(const float4*)(b1 + 4 * c4);
    a.x += bias.x; a.y += bias.y; a.z += bias.z; a.w += bias.w;

    float s1 = a.x + a.y + a.z + a.w;
    float s2 = a.x*a.x + a.y*a.y + a.z*a.z + a.w*a.w;
    #pragma unroll
    for (int m = 16; m >= 1; m >>= 1) {
        s1 += __shfl_xor(s1, m, 64);
        s2 += __shfl_xor(s2, m, 64);
    }
    float mean = s1 * (1.f / 128.f);
    float var  = s2 * (1.f / 128.f) - mean * mean;
    float rs   = rsqrtf(var + LN_EPS);

    float4 gam = *(const float4*)(g1 + 4 * c4);
    float4 bet = *(const float4*)(bt1 + 4 * c4);
    float4 out;
    out.x = silu_f((a.x - mean) * rs * gam.x + bet.x);
    out.y = silu_f((a.y - mean) * rs * gam.y + bet.y);
    out.z = silu_f((a.z - mean) * rs * gam.z + bet.z);
    out.w = silu_f((a.w - mean) * rs * gam.w + bet.w);
    *(float4*)(h1 + (size_t)pos * 128 + 4 * c4) = out;
}

// ---------------- Kernel 2a: conv2 (W=3, stride=5, 128->1024) + bias -> y2 (pre-LN)
// grid = 5 seq * 32 ttiles(4 pos) * 4 cochunks(256 co) = 640 blocks, 256 threads.
__global__ __launch_bounds__(256) void k_conv2p(
    const float* __restrict__ h1,   // (3200,128)
    const float* __restrict__ w2,   // (3,128,1024)
    const float* __restrict__ b2,
    float* __restrict__ y2)         // (640,1024)
{
    int cc    = blockIdx.x & 3;
    int ttile = (blockIdx.x >> 2) & 31;
    int seq   = blockIdx.x >> 7;
    int t0  = ttile * 4;
    int co0 = cc * 256;

    __shared__ float xs[18][128];
    int tid  = threadIdx.x;
    int c4   = tid & 63;   // co = co0 + 4*c4
    int trow = tid >> 6;   // 0..3 ; t = t0 + trow

    for (int idx = tid; idx < 18 * 32; idx += 256) {
        int p = idx >> 5, g = idx & 31;
        *(float4*)&xs[p][4 * g] =
            *(const float4*)(h1 + ((size_t)seq * 640 + 5 * t0 + p) * 128 + 4 * g);
    }
    __syncthreads();

    float acc[4] = {0.f, 0.f, 0.f, 0.f};
    int co = co0 + 4 * c4;

    for (int ci = 0; ci < 128; ci++) {
        float x0 = xs[5 * trow + 0][ci];
        float x1 = xs[5 * trow + 1][ci];
        float x2 = xs[5 * trow + 2][ci];
        float4 w0 = *(const float4*)(w2 + ((size_t)(0 * 128 + ci)) * 1024 + co);
        float4 w1v = *(const float4*)(w2 + ((size_t)(1 * 128 + ci)) * 1024 + co);
        float4 w2v = *(const float4*)(w2 + ((size_t)(2 * 128 + ci)) * 1024 + co);
        acc[0] += x0 * w0.x + x1 * w1v.x + x2 * w2v.x;
        acc[1] += x0 * w0.y + x1 * w1v.y + x2 * w2v.y;
        acc[2] += x0 * w0.z + x1 * w1v.z + x2 * w2v.z;
        acc[3] += x0 * w0.w + x1 * w1v.w + x2 * w2v.w;
    }

    float4 bias = *(const float4*)(b2 + co);
    float4 out = make_float4(acc[0] + bias.x, acc[1] + bias.y,
                             acc[2] + bias.z, acc[3] + bias.w);
    int pos = seq * 128 + t0 + trow;   // 0..639
    *(float4*)(y2 + (size_t)pos * 1024 + co) = out;
}

// ---------------- Kernel 2b: LN(1024) + SiLU -> vp (d_out) / sp (ws)
// grid = 640 blocks (one position each), 256 threads.
__global__ __launch_bounds__(256) void k_ln2(
    const float* __restrict__ y2,   // (640,1024)
    const float* __restrict__ g2,
    const float* __restrict__ bt2,
    float* __restrict__ vp,         // (512,1024)
    float* __restrict__ sp)         // (128,1024)
{
    int pos = blockIdx.x;
    int tid = threadIdx.x, lane = tid & 63, wv = tid >> 6;
    __shared__ float red[4][2];

    float4 a = *(const float4*)(y2 + (size_t)pos * 1024 + 4 * tid);
    float s1 = a.x + a.y + a.z + a.w;
    float s2 = a.x*a.x + a.y*a.y + a.z*a.z + a.w*a.w;
    #pragma unroll
    for (int m = 32; m >= 1; m >>= 1) {
        s1 += __shfl_xor(s1, m, 64);
        s2 += __shfl_xor(s2, m, 64);
    }
    if (lane == 0) { red[wv][0] = s1; red[wv][1] = s2; }
    __syncthreads();
    float S1 = red[0][0] + red[1][0] + red[2][0] + red[3][0];
    float S2 = red[0][1] + red[1][1] + red[2][1] + red[3][1];
    float mean = S1 * (1.f / 1024.f);
    float var  = S2 * (1.f / 1024.f) - mean * mean;
    float rs   = rsqrtf(var + LN_EPS);

    float4 gam = *(const float4*)(g2 + 4 * tid);
    float4 bet = *(const float4*)(bt2 + 4 * tid);
    float4 out;
    out.x = silu_f((a.x - mean) * rs * gam.x + bet.x);
    out.y = silu_f((a.y - mean) * rs * gam.y + bet.y);
    out.z = silu_f((a.z - mean) * rs * gam.z + bet.z);
    out.w = silu_f((a.w - mean) * rs * gam.w + bet.w);
    if (pos < 512)
        *(float4*)(vp + (size_t)pos * 1024 + 4 * tid) = out;
    else
        *(float4*)(sp + (size_t)(pos - 512) * 1024 + 4 * tid) = out;
}

// ---------------- Kernel 3: sign-similarity attention, 2 j's per block
// grid = 4*64 = 256 blocks, 256 threads.
__global__ __launch_bounds__(256) void k_attn(
    const float* __restrict__ vp,   // (4,128,1024)
    const float* __restrict__ sp,   // (128,1024)
    float* __restrict__ O)          // (4,128,1024)
{
    int b  = blockIdx.x >> 6;
    int jp = blockIdx.x & 63;
    int j0 = jp * 2;
    int tid = threadIdx.x, lane = tid & 63, wv = tid >> 6;

    __shared__ int   psh[128][4];
    __shared__ float sc0[128], sc1[128];
    __shared__ float redm[2][4], reds[2][4];

    float4 s0 = *(const float4*)(sp + (size_t)j0 * 1024 + 4 * tid);
    float4 s1 = *(const float4*)(sp + (size_t)(j0 + 1) * 1024 + 4 * tid);
    const float* vpb = vp + (size_t)b * 128 * 1024;

    for (int i = 0; i < 128; i++) {
        float4 v = *(const float4*)(vpb + (size_t)i * 1024 + 4 * tid);
        int m0 = mism1(v.x, s0.x) + mism1(v.y, s0.y) + mism1(v.z, s0.z) + mism1(v.w, s0.w);
        int m1 = mism1(v.x, s1.x) + mism1(v.y, s1.y) + mism1(v.z, s1.z) + mism1(v.w, s1.w);
        int pk = m0 | (m1 << 16);
        #pragma unroll
        for (int m = 32; m >= 1; m >>= 1) pk += __shfl_xor(pk, m, 64);
        if (lane == 0) psh[i][wv] = pk;
    }
    __syncthreads();

    float S0v = -INFINITY, S1v = -INFINITY;
    if (tid < 128) {
        int pk = psh[tid][0] + psh[tid][1] + psh[tid][2] + psh[tid][3];
        int M0 = pk & 0xffff, M1 = pk >> 16;
        S0v = 1.f - (float)M0 * (2.f / 1024.f);
        S1v = 1.f - (float)M1 * (2.f / 1024.f);
    }
    // block max per j
    float m0v = S0v, m1v = S1v;
    #pragma unroll
    for (int m = 32; m >= 1; m >>= 1) {
        m0v = fmaxf(m0v, __shfl_xor(m0v, m, 64));
        m1v = fmaxf(m1v, __shfl_xor(m1v, m, 64));
    }
    if (lane == 0) { redm[0][wv] = m0v; redm[1][wv] = m1v; }
    __syncthreads();
    float mx0 = fmaxf(fmaxf(redm[0][0], redm[0][1]), fmaxf(redm[0][2], redm[0][3]));
    float mx1 = fmaxf(fmaxf(redm[1][0], redm[1][1]), fmaxf(redm[1][2], redm[1][3]));

    float e0 = (tid < 128) ? expf(S0v - mx0) : 0.f;
    float e1 = (tid < 128) ? expf(S1v - mx1) : 0.f;
    float t0 = e0, t1 = e1;
    #pragma unroll
    for (int m = 32; m >= 1; m >>= 1) {
        t0 += __shfl_xor(t0, m, 64);
        t1 += __shfl_xor(t1, m, 64);
    }
    if (lane == 0) { reds[0][wv] = t0; reds[1][wv] = t1; }
    __syncthreads();
    float tot0 = reds[0][0] + reds[0][1] + reds[0][2] + reds[0][3];
    float tot1 = reds[1][0] + reds[1][1] + reds[1][2] + reds[1][3];
    if (tid < 128) { sc0[tid] = e0 / tot0; sc1[tid] = e1 / tot1; }
    __syncthreads();

    float4 ao0 = make_float4(0.f, 0.f, 0.f, 0.f);
    float4 ao1 = make_float4(0.f, 0.f, 0.f, 0.f);
    for (int i = 0; i < 128; i++) {
        float4 v = *(const float4*)(vpb + (size_t)i * 1024 + 4 * tid);
        float f0 = sc0[i], f1 = sc1[i];
        ao0.x += f0 * v.x; ao0.y += f0 * v.y; ao0.z += f0 * v.z; ao0.w += f0 * v.w;
        ao1.x += f1 * v.x; ao1.y += f1 * v.y; ao1.z += f1 * v.z; ao1.w += f1 * v.w;
    }
    float4 o0, o1;
    o0.x = silu_f(ao0.x * s0.x); o0.y = silu_f(ao0.y * s0.y);
    o0.z = silu_f(ao0.z * s0.z); o0.w = silu_f(ao0.w * s0.w);
    o1.x = silu_f(ao1.x * s1.x); o1.y = silu_f(ao1.y * s1.y);
    o1.z = silu_f(ao1.z * s1.z); o1.w = silu_f(ao1.w * s1.w);
    *(float4*)(O + ((size_t)b * 128 + j0)     * 1024 + 4 * tid) = o0;
    *(float4*)(O + ((size_t)b * 128 + j0 + 1) * 1024 + 4 * tid) = o1;
}

extern "C" void kernel_launch(void* const* d_in, const int* in_sizes, int n_in,
                              void* d_out, int out_size, void* d_ws, size_t ws_size,
                              hipStream_t stream) {
    const float* values  = (const float*)d_in[0];
    const float* symbols = (const float*)d_in[1];
    const float* conv1_w = (const float*)d_in[2];
    const float* conv1_b = (const float*)d_in[3];
    const float* ln1_g   = (const float*)d_in[4];
    const float* ln1_b   = (const float*)d_in[5];
    const float* conv2_w = (const float*)d_in[6];
    const float* conv2_b = (const float*)d_in[7];
    const float* ln2_g   = (const float*)d_in[8];
    const float* ln2_b   = (const float*)d_in[9];

    float* out = (float*)d_out;
    float* O   = out;                       // (4,128,1024)
    float* vp  = out + 4 * 128 * 1024;      // (4,128,1024) = values_projected

    float* part = (float*)d_ws;             // (8,3200,128)  = 3,276,800 floats
    float* h1   = part + 8 * 3200 * 128;    // (3200,128)    =   409,600 floats
    float* y2   = h1 + 3200 * 128;          // (640,1024)    =   655,360 floats
    float* sp   = y2 + 640 * 1024;          // (128,1024)    =   131,072 floats

    k_conv1p<<<800, 256, 0, stream>>>(values, symbols, conv1_w, part);
    k_conv1r<<<400, 256, 0, stream>>>(part, conv1_b, ln1_g, ln1_b, h1);
    k_conv2p<<<640, 256, 0, stream>>>(h1, conv2_w, conv2_b, y2);
    k_ln2<<<640, 256, 0, stream>>>(y2, ln2_g, ln2_b, vp, sp);
    k_attn<<<256, 256, 0, stream>>>(vp, sp, O);
}

// Round 3
// 214.531 us; speedup vs baseline: 1.8985x; 1.1027x over previous
//
#include <hip/hip_runtime.h>
#include <math.h>

#define LN_EPS 1e-3f

__device__ __forceinline__ float silu_f(float x) { return x / (1.f + expf(-x)); }

__device__ __forceinline__ int mism1(float a, float s) {
    unsigned ua = __float_as_uint(a);
    unsigned ub = __float_as_uint(a + s);
    return (int)((ua ^ ub) >> 31);
}

// ---------------- Kernel 1a: conv1 split-K partial GEMM
// grid = 5 seq * 20 ptiles(32 pos) * 8 kchunks(64 ci) = 800 blocks, 256 threads.
__global__ __launch_bounds__(256) void k_conv1p(
    const float* __restrict__ values,   // (4,1920,512)
    const float* __restrict__ symbols,  // (1920,512)
    const float* __restrict__ w1,       // (5,512,128)
    float* __restrict__ part)           // (8,3200,128)
{
    const int T_IN = 1920, E = 512;
    int kc    = blockIdx.x & 7;
    int ptile = (blockIdx.x >> 3) % 20;
    int seq   = blockIdx.x / (8 * 20);
    int t0  = ptile * 32;
    int ci0 = kc * 64;
    const float* x = (seq < 4) ? (values + (size_t)seq * T_IN * E) : symbols;
    int p0 = 3 * t0 - 1;

    __shared__ float xs[98][64];

    int tid  = threadIdx.x;
    int c4   = tid & 31;   // co = 4*c4
    int trow = tid >> 5;   // 0..7

    for (int idx = tid; idx < 98 * 16; idx += 256) {
        int p = idx >> 4, g = idx & 15;
        int gp = p0 + p;
        float4 v = make_float4(0.f, 0.f, 0.f, 0.f);
        if (gp >= 0 && gp < T_IN)
            v = *(const float4*)(x + (size_t)gp * E + ci0 + 4 * g);
        *(float4*)&xs[p][4 * g] = v;
    }
    __syncthreads();

    float acc[4][4];
    #pragma unroll
    for (int k = 0; k < 4; k++)
        #pragma unroll
        for (int e = 0; e < 4; e++) acc[k][e] = 0.f;

    #pragma unroll 2
    for (int ci = 0; ci < 64; ci++) {
        float xv[14];
        #pragma unroll
        for (int m = 0; m < 14; m++) xv[m] = xs[12 * trow + m][ci];
        #pragma unroll
        for (int kw = 0; kw < 5; kw++) {
            float4 w = *(const float4*)(w1 + ((size_t)(kw * 512 + ci0 + ci)) * 128 + 4 * c4);
            #pragma unroll
            for (int dt = 0; dt < 4; dt++) {
                float xvv = xv[3 * dt + kw];
                acc[dt][0] += xvv * w.x;
                acc[dt][1] += xvv * w.y;
                acc[dt][2] += xvv * w.z;
                acc[dt][3] += xvv * w.w;
            }
        }
    }

    #pragma unroll
    for (int dt = 0; dt < 4; dt++) {
        int t = t0 + 4 * trow + dt;
        *(float4*)(part + (((size_t)kc * 3200 + seq * 640 + t)) * 128 + 4 * c4) =
            make_float4(acc[dt][0], acc[dt][1], acc[dt][2], acc[dt][3]);
    }
}

// ---------------- Kernel 1b: reduce 8 partials + bias + LN(128) + SiLU -> h1
__global__ __launch_bounds__(256) void k_conv1r(
    const float* __restrict__ part,  // (8,3200,128)
    const float* __restrict__ b1,
    const float* __restrict__ g1,
    const float* __restrict__ bt1,
    float* __restrict__ h1)          // (3200,128)
{
    int tid = threadIdx.x;
    int c4  = tid & 31;
    int pr  = tid >> 5;
    int pos = blockIdx.x * 8 + pr;

    float4 a = make_float4(0.f, 0.f, 0.f, 0.f);
    #pragma unroll
    for (int kc = 0; kc < 8; kc++) {
        float4 p = *(const float4*)(part + (((size_t)kc * 3200 + pos)) * 128 + 4 * c4);
        a.x += p.x; a.y += p.y; a.z += p.z; a.w += p.w;
    }
    float4 bias = *(const float4*)(b1 + 4 * c4);
    a.x += bias.x; a.y += bias.y; a.z += bias.z; a.w += bias.w;

    float s1 = a.x + a.y + a.z + a.w;
    float s2 = a.x*a.x + a.y*a.y + a.z*a.z + a.w*a.w;
    #pragma unroll
    for (int m = 16; m >= 1; m >>= 1) {
        s1 += __shfl_xor(s1, m, 64);
        s2 += __shfl_xor(s2, m, 64);
    }
    float mean = s1 * (1.f / 128.f);
    float var  = s2 * (1.f / 128.f) - mean * mean;
    float rs   = rsqrtf(var + LN_EPS);

    float4 gam = *(const float4*)(g1 + 4 * c4);
    float4 bet = *(const float4*)(bt1 + 4 * c4);
    float4 out;
    out.x = silu_f((a.x - mean) * rs * gam.x + bet.x);
    out.y = silu_f((a.y - mean) * rs * gam.y + bet.y);
    out.z = silu_f((a.z - mean) * rs * gam.z + bet.z);
    out.w = silu_f((a.w - mean) * rs * gam.w + bet.w);
    *(float4*)(h1 + (size_t)pos * 128 + 4 * c4) = out;
}

// ---------------- Kernel 2a: conv2 (W=3, stride=5, 128->1024) + bias -> y2
__global__ __launch_bounds__(256) void k_conv2p(
    const float* __restrict__ h1,   // (3200,128)
    const float* __restrict__ w2,   // (3,128,1024)
    const float* __restrict__ b2,
    float* __restrict__ y2)         // (640,1024)
{
    int cc    = blockIdx.x & 3;
    int ttile = (blockIdx.x >> 2) & 31;
    int seq   = blockIdx.x >> 7;
    int t0  = ttile * 4;
    int co0 = cc * 256;

    __shared__ float xs[18][128];
    int tid  = threadIdx.x;
    int c4   = tid & 63;
    int trow = tid >> 6;

    for (int idx = tid; idx < 18 * 32; idx += 256) {
        int p = idx >> 5, g = idx & 31;
        *(float4*)&xs[p][4 * g] =
            *(const float4*)(h1 + ((size_t)seq * 640 + 5 * t0 + p) * 128 + 4 * g);
    }
    __syncthreads();

    float acc[4] = {0.f, 0.f, 0.f, 0.f};
    int co = co0 + 4 * c4;

    #pragma unroll 2
    for (int ci = 0; ci < 128; ci++) {
        float x0 = xs[5 * trow + 0][ci];
        float x1 = xs[5 * trow + 1][ci];
        float x2 = xs[5 * trow + 2][ci];
        float4 w0 = *(const float4*)(w2 + ((size_t)(0 * 128 + ci)) * 1024 + co);
        float4 w1v = *(const float4*)(w2 + ((size_t)(1 * 128 + ci)) * 1024 + co);
        float4 w2v = *(const float4*)(w2 + ((size_t)(2 * 128 + ci)) * 1024 + co);
        acc[0] += x0 * w0.x + x1 * w1v.x + x2 * w2v.x;
        acc[1] += x0 * w0.y + x1 * w1v.y + x2 * w2v.y;
        acc[2] += x0 * w0.z + x1 * w1v.z + x2 * w2v.z;
        acc[3] += x0 * w0.w + x1 * w1v.w + x2 * w2v.w;
    }

    float4 bias = *(const float4*)(b2 + co);
    float4 out = make_float4(acc[0] + bias.x, acc[1] + bias.y,
                             acc[2] + bias.z, acc[3] + bias.w);
    int pos = seq * 128 + t0 + trow;
    *(float4*)(y2 + (size_t)pos * 1024 + co) = out;
}

// ---------------- Kernel 2b: LN(1024) + SiLU -> vp / sp
__global__ __launch_bounds__(256) void k_ln2(
    const float* __restrict__ y2,   // (640,1024)
    const float* __restrict__ g2,
    const float* __restrict__ bt2,
    float* __restrict__ vp,         // (512,1024)
    float* __restrict__ sp)         // (128,1024)
{
    int pos = blockIdx.x;
    int tid = threadIdx.x, lane = tid & 63, wv = tid >> 6;
    __shared__ float red[4][2];

    float4 a = *(const float4*)(y2 + (size_t)pos * 1024 + 4 * tid);
    float s1 = a.x + a.y + a.z + a.w;
    float s2 = a.x*a.x + a.y*a.y + a.z*a.z + a.w*a.w;
    #pragma unroll
    for (int m = 32; m >= 1; m >>= 1) {
        s1 += __shfl_xor(s1, m, 64);
        s2 += __shfl_xor(s2, m, 64);
    }
    if (lane == 0) { red[wv][0] = s1; red[wv][1] = s2; }
    __syncthreads();
    float S1 = red[0][0] + red[1][0] + red[2][0] + red[3][0];
    float S2 = red[0][1] + red[1][1] + red[2][1] + red[3][1];
    float mean = S1 * (1.f / 1024.f);
    float var  = S2 * (1.f / 1024.f) - mean * mean;
    float rs   = rsqrtf(var + LN_EPS);

    float4 gam = *(const float4*)(g2 + 4 * tid);
    float4 bet = *(const float4*)(bt2 + 4 * tid);
    float4 out;
    out.x = silu_f((a.x - mean) * rs * gam.x + bet.x);
    out.y = silu_f((a.y - mean) * rs * gam.y + bet.y);
    out.z = silu_f((a.z - mean) * rs * gam.z + bet.z);
    out.w = silu_f((a.w - mean) * rs * gam.w + bet.w);
    if (pos < 512)
        *(float4*)(vp + (size_t)pos * 1024 + 4 * tid) = out;
    else
        *(float4*)(sp + (size_t)(pos - 512) * 1024 + 4 * tid) = out;
}

// ---------------- Kernel 3a: mismatch counts, no in-loop reductions
// grid = 4b * 128j = 512 blocks, 256 threads: thread = (i = tid&127, half = tid>>7)
__global__ __launch_bounds__(256) void k_attn_cnt(
    const float* __restrict__ vp,   // (512,1024)
    const float* __restrict__ sp,   // (128,1024)
    int* __restrict__ cnt)          // (4,128,128)
{
    int b = blockIdx.x >> 7;
    int j = blockIdx.x & 127;
    int tid = threadIdx.x;
    int i = tid & 127, half = tid >> 7;

    const float* vrow = vp + ((size_t)(b * 128 + i)) * 1024 + half * 512;
    const float* srow = sp + (size_t)j * 1024 + half * 512;

    int m = 0;
    #pragma unroll 4
    for (int k = 0; k < 128; k++) {
        float4 v = *(const float4*)(vrow + 4 * k);
        float4 s = *(const float4*)(srow + 4 * k);
        m += mism1(v.x, s.x) + mism1(v.y, s.y) + mism1(v.z, s.z) + mism1(v.w, s.w);
    }

    __shared__ int cc[2][128];
    cc[half][i] = m;
    __syncthreads();
    if (tid < 128)
        cnt[((size_t)b * 128 + j) * 128 + tid] = cc[0][tid] + cc[1][tid];
}

// ---------------- Kernel 3b: softmax (per wave) + einsum + silu
// grid = 4b * 32 jquad * 4 dquarter = 512 blocks, 256 threads.
__global__ __launch_bounds__(256) void k_attn_out(
    const int*   __restrict__ cnt,  // (4,128,128)
    const float* __restrict__ vp,   // (512,1024)
    const float* __restrict__ sp,   // (128,1024)
    float* __restrict__ O)          // (4,128,1024)
{
    int b  = blockIdx.x >> 7;
    int r  = blockIdx.x & 127;
    int j0 = (r >> 2) * 4;
    int d0 = (r & 3) * 256;
    int tid = threadIdx.x, lane = tid & 63, w = tid >> 6;
    int j = j0 + w;

    __shared__ float sc[4][128];

    const int* crow = cnt + ((size_t)b * 128 + j) * 128;
    int c0 = crow[lane], c1 = crow[lane + 64];
    float S0 = 1.f - (float)c0 * (2.f / 1024.f);
    float S1 = 1.f - (float)c1 * (2.f / 1024.f);
    float mx = fmaxf(S0, S1);
    #pragma unroll
    for (int m = 32; m >= 1; m >>= 1) mx = fmaxf(mx, __shfl_xor(mx, m, 64));
    float e0 = expf(S0 - mx), e1 = expf(S1 - mx);
    float sm = e0 + e1;
    #pragma unroll
    for (int m = 32; m >= 1; m >>= 1) sm += __shfl_xor(sm, m, 64);
    float inv = 1.f / sm;
    sc[w][lane]      = e0 * inv;
    sc[w][lane + 64] = e1 * inv;
    __syncthreads();

    int dd = d0 + 4 * lane;
    const float* vpb = vp + (size_t)b * 131072;
    float4 ao = make_float4(0.f, 0.f, 0.f, 0.f);
    #pragma unroll 4
    for (int i = 0; i < 128; i++) {
        float4 v = *(const float4*)(vpb + (size_t)i * 1024 + dd);
        float f = sc[w][i];
        ao.x += f * v.x; ao.y += f * v.y; ao.z += f * v.z; ao.w += f * v.w;
    }
    float4 s = *(const float4*)(sp + (size_t)j * 1024 + dd);
    float4 o;
    o.x = silu_f(ao.x * s.x);
    o.y = silu_f(ao.y * s.y);
    o.z = silu_f(ao.z * s.z);
    o.w = silu_f(ao.w * s.w);
    *(float4*)(O + ((size_t)b * 128 + j) * 1024 + dd) = o;
}

extern "C" void kernel_launch(void* const* d_in, const int* in_sizes, int n_in,
                              void* d_out, int out_size, void* d_ws, size_t ws_size,
                              hipStream_t stream) {
    const float* values  = (const float*)d_in[0];
    const float* symbols = (const float*)d_in[1];
    const float* conv1_w = (const float*)d_in[2];
    const float* conv1_b = (const float*)d_in[3];
    const float* ln1_g   = (const float*)d_in[4];
    const float* ln1_b   = (const float*)d_in[5];
    const float* conv2_w = (const float*)d_in[6];
    const float* conv2_b = (const float*)d_in[7];
    const float* ln2_g   = (const float*)d_in[8];
    const float* ln2_b   = (const float*)d_in[9];

    float* out = (float*)d_out;
    float* O   = out;                       // (4,128,1024)
    float* vp  = out + 4 * 128 * 1024;      // (4,128,1024)

    float* part = (float*)d_ws;             // (8,3200,128)
    float* h1   = part + 8 * 3200 * 128;    // (3200,128)
    float* y2   = h1 + 3200 * 128;          // (640,1024)
    float* sp   = y2 + 640 * 1024;          // (128,1024)
    int*   cnt  = (int*)(sp + 128 * 1024);  // (4,128,128)

    k_conv1p<<<800, 256, 0, stream>>>(values, symbols, conv1_w, part);
    k_conv1r<<<400, 256, 0, stream>>>(part, conv1_b, ln1_g, ln1_b, h1);
    k_conv2p<<<640, 256, 0, stream>>>(h1, conv2_w, conv2_b, y2);
    k_ln2<<<640, 256, 0, stream>>>(y2, ln2_g, ln2_b, vp, sp);
    k_attn_cnt<<<512, 256, 0, stream>>>(vp, sp, cnt);
    k_attn_out<<<512, 256, 0, stream>>>(cnt, vp, sp, O);
}